// Round 3
// baseline (221.277 us; speedup 1.0000x reference)
//
#include <hip/hip_runtime.h>
#include <math.h>

#define NN 50000
#define NE 800000
#define NEG 0.2f
#define MAXD 64   // in-degree is ~Poisson(16); P(deg>64) ~ 2e-18 -> fixed-stride CSR is safe

#define GEMM1_BLOCKS ((NN + 63) / 64)     // 782
#define BUILD_GROUPS 8                    // one node-range per XCD (L2 locality)
#define BUILD_BPG 128                     // blocks per group
#define BUILD_BLOCKS (BUILD_GROUPS * BUILD_BPG)   // 1024
#define NODES_PER_GROUP (NN / BUILD_GROUPS)       // 6250
#define EDGES_PER_BLOCK (NE / BUILD_BPG)          // 6250

static __device__ __forceinline__ float lrelu(float v){ return v >= 0.f ? v : NEG * v; }
static __device__ __forceinline__ unsigned f2bf(float f){
    unsigned u = __float_as_uint(f);
    return (u + 0x7fffu + ((u >> 16) & 1u)) >> 16;
}

// ---------------- fused: [blocks 0..781] Layer-1 GEMM  |  [blocks 782..1805] CSR build ----------
// Build is XCD-partitioned: group r = blockIdx%8 (round-robin dispatch => same XCD) handles only
// dst nodes in [r*6250, (r+1)*6250). Its csr slice is 1.6 MB < 4 MiB L2 -> scatter lines stay
// resident and write back once (was: 12.8 MB random scatter -> 51 MB amplified HBM writes).
// Every edge is processed exactly once regardless of the real block->XCD mapping (perf-only hint).
__global__ __launch_bounds__(256) void k_build_gemm1(const int* __restrict__ src, const int* __restrict__ dst,
                                                     int* __restrict__ cnt, int* __restrict__ csr,
                                                     const float* __restrict__ x, const float* __restrict__ W,
                                                     const float* __restrict__ asv, const float* __restrict__ adv,
                                                     unsigned short* __restrict__ xpb, float* __restrict__ as_out,
                                                     float* __restrict__ ad_out){
    __shared__ float xt[64 * 128];
    int t = threadIdx.x;

    if (blockIdx.x >= GEMM1_BLOCKS){
        // ---- CSR build path: scan edge chunk, filter by dst range, histogram+scatter ----
        int i = blockIdx.x - GEMM1_BLOCKS;        // 0..1023
        int r = blockIdx.x & 7;                   // approx XCD id under round-robin dispatch
        int m = i >> 3;                           // chunk index 0..127 (complete per group: (i&7) fixes r)
        int lo = r * NODES_PER_GROUP;
        int hi = lo + NODES_PER_GROUP;
        int e0 = m * EDGES_PER_BLOCK;
        int e1 = e0 + EDGES_PER_BLOCK;
        for (int e = e0 + t; e < e1; e += 256){
            int d = dst[e];
            if (d >= lo && d < hi){
                int slot = atomicAdd(&cnt[d], 1);
                if (slot < MAXD) csr[(size_t)d * MAXD + slot] = src[e];
            }
        }
        return;
    }

    // ---- Layer 1 GEMM path: xp(bf16) = x @ W1 (+ fp32 a_s/a_d) ----
    int m0 = blockIdx.x * 64;
    {
        float4* dstp = (float4*)xt;
        const float4* xs = (const float4*)x;
#pragma unroll
        for (int i = 0; i < 8; ++i){
            int idx = t + 256 * i;
            int node = m0 + (idx >> 5);
            if (node > NN - 1) node = NN - 1;
            dstp[idx] = xs[(size_t)node * 32 + (idx & 31)];
        }
    }
    __syncthreads();
    int tx = t & 31;
    int ty = t >> 5;
    const float4* Wv = (const float4*)W;
    float4 acc[8];
#pragma unroll
    for (int i = 0; i < 8; ++i) acc[i] = make_float4(0.f, 0.f, 0.f, 0.f);
#pragma unroll 2
    for (int kk = 0; kk < 128; kk += 4){
        float4 w0 = Wv[(kk + 0) * 32 + tx];
        float4 w1 = Wv[(kk + 1) * 32 + tx];
        float4 w2 = Wv[(kk + 2) * 32 + tx];
        float4 w3 = Wv[(kk + 3) * 32 + tx];
#pragma unroll
        for (int i = 0; i < 8; ++i){
            float4 xv = *(const float4*)&xt[(ty + 8 * i) * 128 + kk];
            acc[i].x = fmaf(xv.x, w0.x, acc[i].x); acc[i].y = fmaf(xv.x, w0.y, acc[i].y);
            acc[i].z = fmaf(xv.x, w0.z, acc[i].z); acc[i].w = fmaf(xv.x, w0.w, acc[i].w);
            acc[i].x = fmaf(xv.y, w1.x, acc[i].x); acc[i].y = fmaf(xv.y, w1.y, acc[i].y);
            acc[i].z = fmaf(xv.y, w1.z, acc[i].z); acc[i].w = fmaf(xv.y, w1.w, acc[i].w);
            acc[i].x = fmaf(xv.z, w2.x, acc[i].x); acc[i].y = fmaf(xv.z, w2.y, acc[i].y);
            acc[i].z = fmaf(xv.z, w2.z, acc[i].z); acc[i].w = fmaf(xv.z, w2.w, acc[i].w);
            acc[i].x = fmaf(xv.w, w3.x, acc[i].x); acc[i].y = fmaf(xv.w, w3.y, acc[i].y);
            acc[i].z = fmaf(xv.w, w3.z, acc[i].z); acc[i].w = fmaf(xv.w, w3.w, acc[i].w);
        }
    }
    float4 a_s = ((const float4*)asv)[tx];
    float4 a_d = ((const float4*)adv)[tx];
    int head = tx >> 3;
#pragma unroll
    for (int i = 0; i < 8; ++i){
        int node = m0 + ty + 8 * i;
        float ps = acc[i].x * a_s.x + acc[i].y * a_s.y + acc[i].z * a_s.z + acc[i].w * a_s.w;
        float pd = acc[i].x * a_d.x + acc[i].y * a_d.y + acc[i].z * a_d.z + acc[i].w * a_d.w;
        ps += __shfl_xor(ps, 1); pd += __shfl_xor(pd, 1);
        ps += __shfl_xor(ps, 2); pd += __shfl_xor(pd, 2);
        ps += __shfl_xor(ps, 4); pd += __shfl_xor(pd, 4);
        if (node < NN){
            ushort4 pk;
            pk.x = (unsigned short)f2bf(acc[i].x); pk.y = (unsigned short)f2bf(acc[i].y);
            pk.z = (unsigned short)f2bf(acc[i].z); pk.w = (unsigned short)f2bf(acc[i].w);
            ((ushort4*)xpb)[(size_t)node * 32 + tx] = pk;
            if ((tx & 7) == 0){ as_out[node * 4 + head] = ps; ad_out[node * 4 + head] = pd; }
        }
    }
}

// ---------------- Layer 1 aggregation: one wave per dst node ----------------
// lane = eg*16 + g : edge-subgroup eg (4 edges in flight), channel group g (8 ch = uint4 of bf16).
__global__ __launch_bounds__(256) void k_agg1(const unsigned short* __restrict__ xpb,
                                              const float* __restrict__ asf, const float* __restrict__ adf,
                                              const int* __restrict__ cnt, const int* __restrict__ csr,
                                              const float* __restrict__ b1, unsigned short* __restrict__ hb){
    int t = threadIdx.x; int lane = t & 63;
    int g = lane & 15, eg = lane >> 4;
    int node = blockIdx.x * 4 + (t >> 6);
    int head = g >> 2;
    float adh = adf[node * 4 + head];
    int deg = cnt[node]; if (deg > MAXD) deg = MAXD;
    int sv0 = csr[(size_t)node * MAXD + lane];
    int sAll = (lane < deg) ? sv0 : node;     // sanitize unused slots (poisoned memory)
    const uint4* xp4 = (const uint4*)xpb;
    float acc[8] = {0.f,0.f,0.f,0.f,0.f,0.f,0.f,0.f};
    float l = 0.f;
#pragma unroll 2
    for (int j0 = 0; j0 <= deg; j0 += 4){     // virtual edge j: 0 = self loop, 1..deg = csr
        int j = j0 + eg;
        int jj = j > 0 ? j - 1 : 0;
        int s = __shfl(sAll, jj);
        if (j == 0) s = node;
        bool valid = (j <= deg);
        if (!valid) s = node;
        float e = __expf(lrelu(asf[s * 4 + head] + adh));
        e = valid ? e : 0.f;
        uint4 v = xp4[(size_t)s * 16 + g];
        l += e;
        acc[0] = fmaf(e, __uint_as_float(v.x << 16),         acc[0]);
        acc[1] = fmaf(e, __uint_as_float(v.x & 0xffff0000u), acc[1]);
        acc[2] = fmaf(e, __uint_as_float(v.y << 16),         acc[2]);
        acc[3] = fmaf(e, __uint_as_float(v.y & 0xffff0000u), acc[3]);
        acc[4] = fmaf(e, __uint_as_float(v.z << 16),         acc[4]);
        acc[5] = fmaf(e, __uint_as_float(v.z & 0xffff0000u), acc[5]);
        acc[6] = fmaf(e, __uint_as_float(v.w << 16),         acc[6]);
        acc[7] = fmaf(e, __uint_as_float(v.w & 0xffff0000u), acc[7]);
    }
#pragma unroll
    for (int k = 0; k < 8; ++k){
        acc[k] += __shfl_xor(acc[k], 16);
        acc[k] += __shfl_xor(acc[k], 32);
    }
    l += __shfl_xor(l, 16); l += __shfl_xor(l, 32);
    if (eg == 0){
        float inv = 1.f / l;
        float4 blo = ((const float4*)b1)[g * 2];
        float4 bhi = ((const float4*)b1)[g * 2 + 1];
        float r[8];
        r[0] = acc[0] * inv + blo.x; r[1] = acc[1] * inv + blo.y;
        r[2] = acc[2] * inv + blo.z; r[3] = acc[3] * inv + blo.w;
        r[4] = acc[4] * inv + bhi.x; r[5] = acc[5] * inv + bhi.y;
        r[6] = acc[6] * inv + bhi.z; r[7] = acc[7] * inv + bhi.w;
#pragma unroll
        for (int k = 0; k < 8; ++k) r[k] = r[k] > 0.f ? r[k] : 0.f;   // ReLU
        uint4 pk;
        pk.x = f2bf(r[0]) | (f2bf(r[1]) << 16);
        pk.y = f2bf(r[2]) | (f2bf(r[3]) << 16);
        pk.z = f2bf(r[4]) | (f2bf(r[5]) << 16);
        pk.w = f2bf(r[6]) | (f2bf(r[7]) << 16);
        ((uint4*)hb)[(size_t)node * 16 + g] = pk;
    }
}

// ---------------- Layer 2 GEMM: h2(bf16) = h(bf16) @ W2 (+ fp32 a_s2/a_d2) ----------------
__global__ __launch_bounds__(256) void k_gemm2(const unsigned short* __restrict__ hb, const float* __restrict__ W2,
                                               const float* __restrict__ as2v, const float* __restrict__ ad2v,
                                               unsigned short* __restrict__ h2b, float* __restrict__ as2,
                                               float* __restrict__ ad2){
    __shared__ float ht[64 * 136];
    int t = threadIdx.x;
    int m0 = blockIdx.x * 64;
    {
        const uint4* hb4 = (const uint4*)hb;
#pragma unroll
        for (int i = 0; i < 4; ++i){
            int idx = t + 256 * i;          // 0..1023 ; 16 uint4 per row
            int row = idx >> 4;
            int c8 = idx & 15;
            int node = m0 + row;
            if (node > NN - 1) node = NN - 1;
            uint4 v = hb4[(size_t)node * 16 + c8];
            float* d = &ht[row * 136 + c8 * 8];
            d[0] = __uint_as_float(v.x << 16);         d[1] = __uint_as_float(v.x & 0xffff0000u);
            d[2] = __uint_as_float(v.y << 16);         d[3] = __uint_as_float(v.y & 0xffff0000u);
            d[4] = __uint_as_float(v.z << 16);         d[5] = __uint_as_float(v.z & 0xffff0000u);
            d[6] = __uint_as_float(v.w << 16);         d[7] = __uint_as_float(v.w & 0xffff0000u);
        }
    }
    __syncthreads();
    int tx = t & 7;
    int ty = t >> 3;
    const float4* Wv = (const float4*)W2;
    float4 acc[2] = {make_float4(0.f,0.f,0.f,0.f), make_float4(0.f,0.f,0.f,0.f)};
#pragma unroll 2
    for (int kk = 0; kk < 128; kk += 4){
        float4 w0 = Wv[(kk + 0) * 8 + tx];
        float4 w1 = Wv[(kk + 1) * 8 + tx];
        float4 w2 = Wv[(kk + 2) * 8 + tx];
        float4 w3 = Wv[(kk + 3) * 8 + tx];
#pragma unroll
        for (int i = 0; i < 2; ++i){
            float4 xv = *(const float4*)&ht[(ty + 32 * i) * 136 + kk];
            acc[i].x = fmaf(xv.x, w0.x, acc[i].x); acc[i].y = fmaf(xv.x, w0.y, acc[i].y);
            acc[i].z = fmaf(xv.x, w0.z, acc[i].z); acc[i].w = fmaf(xv.x, w0.w, acc[i].w);
            acc[i].x = fmaf(xv.y, w1.x, acc[i].x); acc[i].y = fmaf(xv.y, w1.y, acc[i].y);
            acc[i].z = fmaf(xv.y, w1.z, acc[i].z); acc[i].w = fmaf(xv.y, w1.w, acc[i].w);
            acc[i].x = fmaf(xv.z, w2.x, acc[i].x); acc[i].y = fmaf(xv.z, w2.y, acc[i].y);
            acc[i].z = fmaf(xv.z, w2.z, acc[i].z); acc[i].w = fmaf(xv.z, w2.w, acc[i].w);
            acc[i].x = fmaf(xv.w, w3.x, acc[i].x); acc[i].y = fmaf(xv.w, w3.y, acc[i].y);
            acc[i].z = fmaf(xv.w, w3.z, acc[i].z); acc[i].w = fmaf(xv.w, w3.w, acc[i].w);
        }
    }
    float4 a_s = ((const float4*)as2v)[tx];
    float4 a_d = ((const float4*)ad2v)[tx];
#pragma unroll
    for (int i = 0; i < 2; ++i){
        int node = m0 + ty + 32 * i;
        float ps = acc[i].x * a_s.x + acc[i].y * a_s.y + acc[i].z * a_s.z + acc[i].w * a_s.w;
        float pd = acc[i].x * a_d.x + acc[i].y * a_d.y + acc[i].z * a_d.z + acc[i].w * a_d.w;
        ps += __shfl_xor(ps, 1); pd += __shfl_xor(pd, 1);
        ps += __shfl_xor(ps, 2); pd += __shfl_xor(pd, 2);
        ps += __shfl_xor(ps, 4); pd += __shfl_xor(pd, 4);
        if (node < NN){
            ushort4 pk;
            pk.x = (unsigned short)f2bf(acc[i].x); pk.y = (unsigned short)f2bf(acc[i].y);
            pk.z = (unsigned short)f2bf(acc[i].z); pk.w = (unsigned short)f2bf(acc[i].w);
            ((ushort4*)h2b)[(size_t)node * 8 + tx] = pk;
            if (tx == 0){ as2[node] = ps; ad2[node] = pd; }
        }
    }
}

// ---------------- Layer 2 aggregation ----------------
// lane = eg*8 + g : 8 edges in flight, channel group g (4 ch = uint2 of bf16).
__global__ __launch_bounds__(256) void k_agg2(const unsigned short* __restrict__ h2b,
                                              const float* __restrict__ as2, const float* __restrict__ ad2,
                                              const int* __restrict__ cnt, const int* __restrict__ csr,
                                              const float* __restrict__ b2, float* __restrict__ out){
    int t = threadIdx.x; int lane = t & 63;
    int g = lane & 7, eg = lane >> 3;
    int node = blockIdx.x * 4 + (t >> 6);
    float adv = ad2[node];
    int deg = cnt[node]; if (deg > MAXD) deg = MAXD;
    int sv0 = csr[(size_t)node * MAXD + lane];
    int sAll = (lane < deg) ? sv0 : node;
    const uint2* h22 = (const uint2*)h2b;
    float acc[4] = {0.f, 0.f, 0.f, 0.f};
    float l = 0.f;
#pragma unroll 2
    for (int j0 = 0; j0 <= deg; j0 += 8){
        int j = j0 + eg;
        int jj = j > 0 ? j - 1 : 0;
        int s = __shfl(sAll, jj);
        if (j == 0) s = node;
        bool valid = (j <= deg);
        if (!valid) s = node;
        float e = __expf(lrelu(as2[s] + adv));
        e = valid ? e : 0.f;
        uint2 v = h22[(size_t)s * 8 + g];
        l += e;
        acc[0] = fmaf(e, __uint_as_float(v.x << 16),         acc[0]);
        acc[1] = fmaf(e, __uint_as_float(v.x & 0xffff0000u), acc[1]);
        acc[2] = fmaf(e, __uint_as_float(v.y << 16),         acc[2]);
        acc[3] = fmaf(e, __uint_as_float(v.y & 0xffff0000u), acc[3]);
    }
#pragma unroll
    for (int k = 0; k < 4; ++k){
        acc[k] += __shfl_xor(acc[k], 8);
        acc[k] += __shfl_xor(acc[k], 16);
        acc[k] += __shfl_xor(acc[k], 32);
    }
    l += __shfl_xor(l, 8); l += __shfl_xor(l, 16); l += __shfl_xor(l, 32);
    if (eg == 0){
        float inv = 1.f / l;
        float4 bv = ((const float4*)b2)[g];
        float4 r;
        r.x = acc[0] * inv + bv.x;
        r.y = acc[1] * inv + bv.y;
        r.z = acc[2] * inv + bv.z;
        r.w = acc[3] * inv + bv.w;
        ((float4*)out)[(size_t)node * 8 + g] = r;
    }
}

extern "C" void kernel_launch(void* const* d_in, const int* in_sizes, int n_in,
                              void* d_out, int out_size, void* d_ws, size_t ws_size,
                              hipStream_t stream){
    const float* x    = (const float*)d_in[0];
    const int*   ei   = (const int*)d_in[1];
    const float* W1   = (const float*)d_in[2];
    const float* as1  = (const float*)d_in[3];
    const float* ad1  = (const float*)d_in[4];
    const float* b1   = (const float*)d_in[5];
    const float* W2   = (const float*)d_in[6];
    const float* as2v = (const float*)d_in[7];
    const float* ad2v = (const float*)d_in[8];
    const float* b2   = (const float*)d_in[9];
    float* out = (float*)d_out;
    const int* srcE = ei;
    const int* dstE = ei + NE;

    char* p = (char*)d_ws;
    auto alloc = [&](size_t bytes) -> char* {
        char* r = p;
        p += (bytes + 255) & ~(size_t)255;
        return r;
    };
    int*   cnt  = (int*)alloc((size_t)NN * 4);
    int*   csr  = (int*)alloc((size_t)NN * MAXD * 4);     // 12.8 MB slot array
    float* as_1 = (float*)alloc((size_t)NN * 16);
    float* ad_1 = (float*)alloc((size_t)NN * 16);
    unsigned short* xpb = (unsigned short*)alloc((size_t)NN * 128 * 2);
    unsigned short* hb  = (unsigned short*)alloc((size_t)NN * 128 * 2);
    // layer-2 intermediates alias xpb (dead after k_agg1)
    unsigned short* h2b = xpb;                            // NN*32 bf16
    float* as_2 = (float*)(xpb + (size_t)NN * 32);        // NN fp32
    float* ad_2 = as_2 + NN;                              // NN fp32

    hipMemsetAsync(cnt, 0, (size_t)NN * 4, stream);
    k_build_gemm1 <<<GEMM1_BLOCKS + BUILD_BLOCKS, 256, 0, stream>>>(srcE, dstE, cnt, csr,
                                                                    x, W1, as1, ad1, xpb, as_1, ad_1);
    k_agg1  <<<NN / 4, 256, 0, stream>>>(xpb, as_1, ad_1, cnt, csr, b1, hb);
    k_gemm2 <<<(NN + 63) / 64, 256, 0, stream>>>(hb, W2, as2v, ad2v, h2b, as_2, ad_2);
    k_agg2  <<<NN / 4, 256, 0, stream>>>(h2b, as_2, ad_2, cnt, csr, b2, out);
}

// Round 6
// 209.221 us; speedup vs baseline: 1.0576x; 1.0576x over previous
//
#include <hip/hip_runtime.h>
#include <math.h>

#define NN 50000
#define NE 800000
#define NEG 0.2f
#define MAXD 64   // in-degree is ~Poisson(16); P(deg>64) ~ 2e-18 -> fixed-stride CSR is safe

#define GEMM1_BLOCKS ((NN + 63) / 64)     // 782
#define BUILD_BLOCKS ((NE + 255) / 256)   // 3125  (simple 1-pass build: measured 60us vs 75-84us partitioned)

static __device__ __forceinline__ float lrelu(float v){ return v >= 0.f ? v : NEG * v; }
static __device__ __forceinline__ unsigned f2bf(float f){
    unsigned u = __float_as_uint(f);
    return (u + 0x7fffu + ((u >> 16) & 1u)) >> 16;
}

// ---------------- fused: [blocks 0..781] Layer-1 GEMM  |  [blocks 782..3906] CSR build ----------
// R3 lesson: XCD-partitioned build cut WRITE 62->46MB but added 22MB FETCH + 8x scan work and
// regressed 60->79us (kernel is latency-bound, not write-BW-bound). Reverted to simple 1-pass.
__global__ __launch_bounds__(256) void k_build_gemm1(const int* __restrict__ src, const int* __restrict__ dst,
                                                     int* __restrict__ cnt, int* __restrict__ csr,
                                                     const float* __restrict__ x, const float* __restrict__ W,
                                                     const float* __restrict__ asv, const float* __restrict__ adv,
                                                     unsigned short* __restrict__ xpb, float* __restrict__ as_out,
                                                     float* __restrict__ ad_out){
    __shared__ float xt[64 * 128];
    int t = threadIdx.x;

    if (blockIdx.x >= GEMM1_BLOCKS){
        // ---- CSR build path: histogram + scatter in one pass ----
        int e = (blockIdx.x - GEMM1_BLOCKS) * 256 + t;
        if (e < NE){
            int d = dst[e];
            int slot = atomicAdd(&cnt[d], 1);
            if (slot < MAXD) csr[(size_t)d * MAXD + slot] = src[e];
        }
        return;
    }

    // ---- Layer 1 GEMM path: xp(bf16) = x @ W1 (+ fp32 a_s/a_d) ----
    int m0 = blockIdx.x * 64;
    {
        float4* dstp = (float4*)xt;
        const float4* xs = (const float4*)x;
#pragma unroll
        for (int i = 0; i < 8; ++i){
            int idx = t + 256 * i;
            int node = m0 + (idx >> 5);
            if (node > NN - 1) node = NN - 1;
            dstp[idx] = xs[(size_t)node * 32 + (idx & 31)];
        }
    }
    __syncthreads();
    int tx = t & 31;
    int ty = t >> 5;
    const float4* Wv = (const float4*)W;
    float4 acc[8];
#pragma unroll
    for (int i = 0; i < 8; ++i) acc[i] = make_float4(0.f, 0.f, 0.f, 0.f);
#pragma unroll 2
    for (int kk = 0; kk < 128; kk += 4){
        float4 w0 = Wv[(kk + 0) * 32 + tx];
        float4 w1 = Wv[(kk + 1) * 32 + tx];
        float4 w2 = Wv[(kk + 2) * 32 + tx];
        float4 w3 = Wv[(kk + 3) * 32 + tx];
#pragma unroll
        for (int i = 0; i < 8; ++i){
            float4 xv = *(const float4*)&xt[(ty + 8 * i) * 128 + kk];
            acc[i].x = fmaf(xv.x, w0.x, acc[i].x); acc[i].y = fmaf(xv.x, w0.y, acc[i].y);
            acc[i].z = fmaf(xv.x, w0.z, acc[i].z); acc[i].w = fmaf(xv.x, w0.w, acc[i].w);
            acc[i].x = fmaf(xv.y, w1.x, acc[i].x); acc[i].y = fmaf(xv.y, w1.y, acc[i].y);
            acc[i].z = fmaf(xv.y, w1.z, acc[i].z); acc[i].w = fmaf(xv.y, w1.w, acc[i].w);
            acc[i].x = fmaf(xv.z, w2.x, acc[i].x); acc[i].y = fmaf(xv.z, w2.y, acc[i].y);
            acc[i].z = fmaf(xv.z, w2.z, acc[i].z); acc[i].w = fmaf(xv.z, w2.w, acc[i].w);
            acc[i].x = fmaf(xv.w, w3.x, acc[i].x); acc[i].y = fmaf(xv.w, w3.y, acc[i].y);
            acc[i].z = fmaf(xv.w, w3.z, acc[i].z); acc[i].w = fmaf(xv.w, w3.w, acc[i].w);
        }
    }
    float4 a_s = ((const float4*)asv)[tx];
    float4 a_d = ((const float4*)adv)[tx];
    int head = tx >> 3;
#pragma unroll
    for (int i = 0; i < 8; ++i){
        int node = m0 + ty + 8 * i;
        float ps = acc[i].x * a_s.x + acc[i].y * a_s.y + acc[i].z * a_s.z + acc[i].w * a_s.w;
        float pd = acc[i].x * a_d.x + acc[i].y * a_d.y + acc[i].z * a_d.z + acc[i].w * a_d.w;
        ps += __shfl_xor(ps, 1); pd += __shfl_xor(pd, 1);
        ps += __shfl_xor(ps, 2); pd += __shfl_xor(pd, 2);
        ps += __shfl_xor(ps, 4); pd += __shfl_xor(pd, 4);
        if (node < NN){
            ushort4 pk;
            pk.x = (unsigned short)f2bf(acc[i].x); pk.y = (unsigned short)f2bf(acc[i].y);
            pk.z = (unsigned short)f2bf(acc[i].z); pk.w = (unsigned short)f2bf(acc[i].w);
            ((ushort4*)xpb)[(size_t)node * 32 + tx] = pk;
            if ((tx & 7) == 0){ as_out[node * 4 + head] = ps; ad_out[node * 4 + head] = pd; }
        }
    }
}

// ---------------- Layer 1 aggregation FUSED with Layer 2 GEMM ----------------
// Aggregation: lane = eg*16 + g (4 edges in flight, 8 ch per lane). The finished h-row
// (bias+ReLU, full f32) goes to LDS instead of global; then each wave does the 128x32 GEMV
// against LDS-staged W2 and emits h2b(bf16) + as2/ad2 directly. hb never exists in global.
__global__ __launch_bounds__(256) void k_agg1g2(const unsigned short* __restrict__ xpb,
                                                const float* __restrict__ asf, const float* __restrict__ adf,
                                                const int* __restrict__ cnt, const int* __restrict__ csr,
                                                const float* __restrict__ b1, const float* __restrict__ W2,
                                                const float* __restrict__ as2v, const float* __restrict__ ad2v,
                                                unsigned short* __restrict__ h2b, float* __restrict__ as2o,
                                                float* __restrict__ ad2o){
    __shared__ float w2s[128 * 32];     // 16 KB
    __shared__ float hrow[4][128];      // 2 KB
    int t = threadIdx.x; int lane = t & 63;
    int widx = t >> 6;
    {   // stage W2 (consumed after the same barrier that publishes hrow)
        float4* d = (float4*)w2s;
        const float4* s = (const float4*)W2;
#pragma unroll
        for (int i = 0; i < 4; ++i) d[t + 256 * i] = s[t + 256 * i];
    }
    int g = lane & 15, eg = lane >> 4;
    int node = blockIdx.x * 4 + widx;
    int head = g >> 2;
    float adh = adf[node * 4 + head];
    int deg = cnt[node]; if (deg > MAXD) deg = MAXD;
    int sv0 = csr[(size_t)node * MAXD + lane];
    int sAll = (lane < deg) ? sv0 : node;     // sanitize unused slots (poisoned memory)
    const uint4* xp4 = (const uint4*)xpb;
    float acc[8] = {0.f,0.f,0.f,0.f,0.f,0.f,0.f,0.f};
    float l = 0.f;
#pragma unroll 2
    for (int j0 = 0; j0 <= deg; j0 += 4){     // virtual edge j: 0 = self loop, 1..deg = csr
        int j = j0 + eg;
        int jj = j > 0 ? j - 1 : 0;
        int s = __shfl(sAll, jj);
        if (j == 0) s = node;
        bool valid = (j <= deg);
        if (!valid) s = node;
        float e = __expf(lrelu(asf[s * 4 + head] + adh));
        e = valid ? e : 0.f;
        uint4 v = xp4[(size_t)s * 16 + g];
        l += e;
        acc[0] = fmaf(e, __uint_as_float(v.x << 16),         acc[0]);
        acc[1] = fmaf(e, __uint_as_float(v.x & 0xffff0000u), acc[1]);
        acc[2] = fmaf(e, __uint_as_float(v.y << 16),         acc[2]);
        acc[3] = fmaf(e, __uint_as_float(v.y & 0xffff0000u), acc[3]);
        acc[4] = fmaf(e, __uint_as_float(v.z << 16),         acc[4]);
        acc[5] = fmaf(e, __uint_as_float(v.z & 0xffff0000u), acc[5]);
        acc[6] = fmaf(e, __uint_as_float(v.w << 16),         acc[6]);
        acc[7] = fmaf(e, __uint_as_float(v.w & 0xffff0000u), acc[7]);
    }
#pragma unroll
    for (int k = 0; k < 8; ++k){
        acc[k] += __shfl_xor(acc[k], 16);
        acc[k] += __shfl_xor(acc[k], 32);
    }
    l += __shfl_xor(l, 16); l += __shfl_xor(l, 32);
    if (eg == 0){
        float inv = 1.f / l;
        float4 blo = ((const float4*)b1)[g * 2];
        float4 bhi = ((const float4*)b1)[g * 2 + 1];
        float r[8];
        r[0] = acc[0] * inv + blo.x; r[1] = acc[1] * inv + blo.y;
        r[2] = acc[2] * inv + blo.z; r[3] = acc[3] * inv + blo.w;
        r[4] = acc[4] * inv + bhi.x; r[5] = acc[5] * inv + bhi.y;
        r[6] = acc[6] * inv + bhi.z; r[7] = acc[7] * inv + bhi.w;
        float* hr = hrow[widx];
#pragma unroll
        for (int k = 0; k < 8; ++k) hr[g * 8 + k] = r[k] > 0.f ? r[k] : 0.f;   // ReLU
    }
    __syncthreads();
    // ---- per-wave 128x32 GEMV: h2 = h @ W2 ; split-K across wave halves ----
    int c = lane & 31;
    int kbase = (lane >> 5) << 6;            // 0 or 64
    const float* hr = hrow[widx];
    float h2 = 0.f;
#pragma unroll 8
    for (int k = 0; k < 64; ++k){
        h2 = fmaf(hr[kbase + k], w2s[(kbase + k) * 32 + c], h2);   // broadcast + conflict-free
    }
    h2 += __shfl_xor(h2, 32);                // lanes c and c+32 now both hold h2[c]
    float hn = __shfl_xor(h2, 1);            // partner channel for bf16 pack
    float ps = h2 * as2v[c];
    float pd = h2 * ad2v[c];
    ps += __shfl_xor(ps, 1);  pd += __shfl_xor(pd, 1);
    ps += __shfl_xor(ps, 2);  pd += __shfl_xor(pd, 2);
    ps += __shfl_xor(ps, 4);  pd += __shfl_xor(pd, 4);
    ps += __shfl_xor(ps, 8);  pd += __shfl_xor(pd, 8);
    ps += __shfl_xor(ps, 16); pd += __shfl_xor(pd, 16);
    if (lane == 0){ as2o[node] = ps; ad2o[node] = pd; }
    if (lane < 32 && !(lane & 1)){
        ((unsigned*)h2b)[(size_t)node * 16 + (lane >> 1)] = f2bf(h2) | (f2bf(hn) << 16);
    }
}

// ---------------- Layer 2 aggregation ----------------
// lane = eg*8 + g : 8 edges in flight, channel group g (4 ch = uint2 of bf16).
__global__ __launch_bounds__(256) void k_agg2(const unsigned short* __restrict__ h2b,
                                              const float* __restrict__ as2, const float* __restrict__ ad2,
                                              const int* __restrict__ cnt, const int* __restrict__ csr,
                                              const float* __restrict__ b2, float* __restrict__ out){
    int t = threadIdx.x; int lane = t & 63;
    int g = lane & 7, eg = lane >> 3;
    int node = blockIdx.x * 4 + (t >> 6);
    float adv = ad2[node];
    int deg = cnt[node]; if (deg > MAXD) deg = MAXD;
    int sv0 = csr[(size_t)node * MAXD + lane];
    int sAll = (lane < deg) ? sv0 : node;
    const uint2* h22 = (const uint2*)h2b;
    float acc[4] = {0.f, 0.f, 0.f, 0.f};
    float l = 0.f;
#pragma unroll 2
    for (int j0 = 0; j0 <= deg; j0 += 8){
        int j = j0 + eg;
        int jj = j > 0 ? j - 1 : 0;
        int s = __shfl(sAll, jj);
        if (j == 0) s = node;
        bool valid = (j <= deg);
        if (!valid) s = node;
        float e = __expf(lrelu(as2[s] + adv));
        e = valid ? e : 0.f;
        uint2 v = h22[(size_t)s * 8 + g];
        l += e;
        acc[0] = fmaf(e, __uint_as_float(v.x << 16),         acc[0]);
        acc[1] = fmaf(e, __uint_as_float(v.x & 0xffff0000u), acc[1]);
        acc[2] = fmaf(e, __uint_as_float(v.y << 16),         acc[2]);
        acc[3] = fmaf(e, __uint_as_float(v.y & 0xffff0000u), acc[3]);
    }
#pragma unroll
    for (int k = 0; k < 4; ++k){
        acc[k] += __shfl_xor(acc[k], 8);
        acc[k] += __shfl_xor(acc[k], 16);
        acc[k] += __shfl_xor(acc[k], 32);
    }
    l += __shfl_xor(l, 8); l += __shfl_xor(l, 16); l += __shfl_xor(l, 32);
    if (eg == 0){
        float inv = 1.f / l;
        float4 bv = ((const float4*)b2)[g];
        float4 r;
        r.x = acc[0] * inv + bv.x;
        r.y = acc[1] * inv + bv.y;
        r.z = acc[2] * inv + bv.z;
        r.w = acc[3] * inv + bv.w;
        ((float4*)out)[(size_t)node * 8 + g] = r;
    }
}

extern "C" void kernel_launch(void* const* d_in, const int* in_sizes, int n_in,
                              void* d_out, int out_size, void* d_ws, size_t ws_size,
                              hipStream_t stream){
    const float* x    = (const float*)d_in[0];
    const int*   ei   = (const int*)d_in[1];
    const float* W1   = (const float*)d_in[2];
    const float* as1  = (const float*)d_in[3];
    const float* ad1  = (const float*)d_in[4];
    const float* b1   = (const float*)d_in[5];
    const float* W2   = (const float*)d_in[6];
    const float* as2v = (const float*)d_in[7];
    const float* ad2v = (const float*)d_in[8];
    const float* b2   = (const float*)d_in[9];
    float* out = (float*)d_out;
    const int* srcE = ei;
    const int* dstE = ei + NE;

    char* p = (char*)d_ws;
    auto alloc = [&](size_t bytes) -> char* {
        char* r = p;
        p += (bytes + 255) & ~(size_t)255;
        return r;
    };
    int*   cnt  = (int*)alloc((size_t)NN * 4);
    int*   csr  = (int*)alloc((size_t)NN * MAXD * 4);     // 12.8 MB slot array
    float* as_1 = (float*)alloc((size_t)NN * 16);
    float* ad_1 = (float*)alloc((size_t)NN * 16);
    unsigned short* xpb = (unsigned short*)alloc((size_t)NN * 128 * 2);
    unsigned short* h2b = (unsigned short*)alloc((size_t)NN * 32 * 2);   // layer-2 features (bf16)
    float* as_2 = (float*)alloc((size_t)NN * 4);
    float* ad_2 = (float*)alloc((size_t)NN * 4);

    hipMemsetAsync(cnt, 0, (size_t)NN * 4, stream);
    k_build_gemm1 <<<GEMM1_BLOCKS + BUILD_BLOCKS, 256, 0, stream>>>(srcE, dstE, cnt, csr,
                                                                    x, W1, as1, ad1, xpb, as_1, ad_1);
    k_agg1g2 <<<NN / 4, 256, 0, stream>>>(xpb, as_1, ad_1, cnt, csr, b1, W2, as2v, ad2v,
                                          h2b, as_2, ad_2);
    k_agg2  <<<NN / 4, 256, 0, stream>>>(h2b, as_2, ad_2, cnt, csr, b2, out);
}